// Round 6
// baseline (591.050 us; speedup 1.0000x reference)
//
#include <hip/hip_runtime.h>
#include <hip/hip_bf16.h>
#include <stdint.h>

// Transformer block: B=8, T=2048, C=1024, fp32 in/out, bf16 MFMA internally.
// Round 6: rescheduled 8-phase 256x256 GEMM — only TWO vmcnt(4) waits per
// iteration (vs four tight ones), 3-6 phases of issue-to-force lookahead,
// WAR-audited stage slots. Swizzle (T2), XCD remap (T1), setprio (T5),
// epilogues and launcher unchanged from round 5.

#define C_DIM 1024
#define T_DIM 2048
#define B_DIM 8

typedef float f32x4 __attribute__((ext_vector_type(4)));
typedef __bf16 bf16x8 __attribute__((ext_vector_type(8)));

typedef const __attribute__((address_space(1))) void gvoid_t;
typedef __attribute__((address_space(3))) void lvoid_t;

__device__ __forceinline__ void gload_lds16(const void* g, void* l) {
    __builtin_amdgcn_global_load_lds((gvoid_t*)g, (lvoid_t*)l, 16, 0, 0);
}

__device__ __forceinline__ unsigned short f2bf_bits(float f) {
    __hip_bfloat16 h = __float2bfloat16(f);
    return *reinterpret_cast<unsigned short*>(&h);
}

// Bijective XCD-chunked remap (m204)
__device__ __forceinline__ void xcd_remap(int& bx, int& by, int& bz) {
    const int gx = gridDim.x, gy = gridDim.y;
    const int nwg = gx * gy * (int)gridDim.z;
    const int orig = bx + gx * (by + gy * bz);
    const int q = nwg >> 3, r = nwg & 7;
    const int xcd = orig & 7, pos = orig >> 3;
    const int neu = (xcd < r ? xcd * (q + 1) : r * (q + 1) + (xcd - r) * q) + pos;
    bx = neu % gx;
    const int t = neu / gx;
    by = t % gy;
    bz = t / gy;
}

#define BAR() do { __builtin_amdgcn_s_barrier(); __builtin_amdgcn_sched_barrier(0); } while(0)
#define VMCNT(n) do { asm volatile("s_waitcnt vmcnt(" #n ")" ::: "memory"); \
                      __builtin_amdgcn_sched_barrier(0); } while(0)

// read A fragments (4 mf x 2 ks) for this wave's rows, quadrant half hq, dbuf buf
#define RDA(buf, hq) do { \
    _Pragma("unroll") \
    for (int mf_ = 0; mf_ < 4; ++mf_) { \
        const char* p_ = lds + (buf)*32768 + wrb + (hq)*8192 + mf_*2048; \
        aF[mf_][0] = *(const bf16x8*)(p_ + offk0); \
        aF[mf_][1] = *(const bf16x8*)(p_ + offk1); \
    } \
} while(0)

// read B fragments (2 n2 x 2 ks) for this wave's cols, N-half nh, dbuf buf
#define RDB(buf, nh) do { \
    _Pragma("unroll") \
    for (int n2_ = 0; n2_ < 2; ++n2_) { \
        const char* p_ = lds + 65536 + (buf)*32768 + wcb + ((nh)*2 + n2_)*2048; \
        bF[nh][n2_][0] = *(const bf16x8*)(p_ + offk0); \
        bF[nh][n2_][1] = *(const bf16x8*)(p_ + offk1); \
    } \
} while(0)

// 16 MFMA for quadrant (Mh,Nh); A regs = current aF (loaded for Mh this phase)
#define MM(Mh, Nh) do { \
    __builtin_amdgcn_s_setprio(1); \
    _Pragma("unroll") \
    for (int m4_ = 0; m4_ < 4; ++m4_) \
    _Pragma("unroll") \
    for (int n2_ = 0; n2_ < 2; ++n2_) \
    _Pragma("unroll") \
    for (int ks_ = 0; ks_ < 2; ++ks_) \
        acc[(Mh)*4 + m4_][(Nh)*2 + n2_] = __builtin_amdgcn_mfma_f32_16x16x32_bf16( \
            aF[m4_][ks_], bF[Nh][n2_][ks_], acc[(Mh)*4 + m4_][(Nh)*2 + n2_], 0, 0, 0); \
    __builtin_amdgcn_s_setprio(0); \
} while(0)

// stage one 16KB half-tile (2 x gload_lds16 per thread)
#define STA(buf, half, kt) do { \
    const int go_ = aoff + (half)*128*lda + (kt)*64; \
    char* lp_ = ldsw + (buf)*32768 + (half)*16384; \
    gload_lds16(A + go_,            lp_); \
    gload_lds16(A + go_ + 64*lda,   lp_ + 8192); \
} while(0)
#define STB(buf, half, kt) do { \
    const int go_ = boff + (half)*128*ldb + (kt)*64; \
    char* lp_ = ldsw + 65536 + (buf)*32768 + (half)*16384; \
    gload_lds16(Bt + go_,           lp_); \
    gload_lds16(Bt + go_ + 64*ldb,  lp_ + 8192); \
} while(0)

// ---------------------------------------------------------------------------
// 256x256 8-phase GEMM: C[M,N] = A[M,K] x Bt[N,K], bf16 in.
// Schedule ledger (steady state, loads per half-tile = 2):
//   entering ph1: outstanding {B0(t+1),A0(t+1)} (4 loads)
//   ph1 issues {A1,B1}(t+1); ph3 B0(t+2); ph4 A0(t+2) -> 12 outstanding
//   ph4 VMCNT(4): forces tile t+1 (8 oldest), leaves {B0,A0}(t+2)
//   ph5 issues {A1,B1}(t+2); ph7 B0(t+3); ph8 A0(t+3) -> 12 outstanding
//   ph8 VMCNT(4): forces tile t+2, leaves {B0,A0}(t+3)  [invariant restored]
// WAR audit (stage -> region's last reader): A halves read ph1,ph3 (per wr);
// B halves read ph1,ph2 (per wc) -> stages at ph3(B0),ph4(A0),ph5(A1,B1) for
// buf0 and ph7(B0),ph8(A0),ph1-next(A1,B1) for buf1 are all after last read.
// EPI: 0 bf16; 2 fp32 + residual R (Cout may alias R); 3 bf16 silu;
//      4 bf16*scale; 6 fused qkv route (Cout=q, C2=k, C3=vT[B][C][T]).
// CMODE: 0 none; 1 causal block skip; 2 causal K clip (kmax = m0+256).
// ---------------------------------------------------------------------------
template<int EPI, int CMODE>
__global__ __launch_bounds__(512, 2)
void gemm256(const __hip_bfloat16* A, const __hip_bfloat16* Bt,
             void* Cout, const float* R, void* C2, void* C3,
             int K, int lda, int ldb, int ldc,
             long long sA, long long sB, long long sC, float scale)
{
    int bx = blockIdx.x, by = blockIdx.y, bz = blockIdx.z;
    xcd_remap(bx, by, bz);
    if constexpr (CMODE == 1) { if (bx > by) return; }

    const int tid  = threadIdx.x;
    const int lane = tid & 63, wave = tid >> 6;
    const int l15  = lane & 15, l4 = lane >> 4;
    const int wr   = wave >> 2, wc = wave & 3;      // 2 x 4 wave grid
    const int m0   = by * 256, n0 = bx * 256;
    const int z    = bz;

    A  += (long long)z * sA;
    Bt += (long long)z * sB;

    __shared__ __align__(16) char lds_[131072];     // A [0,64K), B [64K,128K)
    char* lds  = lds_;
    char* ldsw = lds_ + wave * 1024;

    int kmax = K;
    if constexpr (CMODE == 2) { int km = m0 + 256; kmax = km < K ? km : K; }
    const int NT = kmax >> 6, niter = NT >> 1;

    // read-side lane offsets: row-local byte = l15*128 + ((ks*4+l4)^(l15&7))*16
    const int offk0 = l15 * 128 + (((l4)     ^ (l15 & 7)) << 4);
    const int offk1 = l15 * 128 + (((4 + l4) ^ (l15 & 7)) << 4);
    const int wrb = wr * 16384, wcb = wc * 8192;

    // staging: thread -> (row = tid>>3, slot = (tid&7)^(row&7)); inverse swizzle on src
    const int rowq  = tid >> 3;
    const int sslot = (tid & 7) ^ (rowq & 7);
    const int aoff  = (m0 + rowq) * lda + sslot * 8;
    const int boff  = (n0 + rowq) * ldb + sslot * 8;

    f32x4 acc[8][4];
#pragma unroll
    for (int i = 0; i < 8; ++i)
#pragma unroll
        for (int j = 0; j < 4; ++j) acc[i][j] = (f32x4){0.f, 0.f, 0.f, 0.f};
    bf16x8 aF[4][2], bF[2][2][2];

    // prologue: tile0 all 4 halves + tile1 {B0, A0}; force tile0, keep 2 flying
    STB(0, 0, 0); STA(0, 0, 0); STA(0, 1, 0); STB(0, 1, 0);
    STB(1, 0, 1); STA(1, 0, 1);
    VMCNT(4);
    BAR();

    for (int it = 0; it < niter; ++it) {
        const int t1 = 2 * it + 1;
        const int s2 = (2 * it + 2) % NT, s3 = (2 * it + 3) % NT;
        // ph1: finish tile t1 staging | read A-lo,B-lo of tile 2it (buf0)
        STA(1, 1, t1); STB(1, 1, t1);
        RDA(0, 0); RDB(0, 0);
        BAR(); MM(0, 0); BAR();
        // ph2: read B-hi (A-lo cached)
        RDB(0, 1);
        BAR(); MM(0, 1); BAR();
        // ph3: stage B0(t+2) | read A-hi (B-lo cached)
        STB(0, 0, s2);
        RDA(0, 1);
        BAR(); MM(1, 0); BAR();
        // ph4: stage A0(t+2) | all regs cached | force tile t+1
        STA(0, 0, s2);
        BAR(); MM(1, 1); VMCNT(4); BAR();
        // ph5: stage A1,B1(t+2) | read A-lo,B-lo of tile t+1 (buf1)
        STA(0, 1, s2); STB(0, 1, s2);
        RDA(1, 0); RDB(1, 0);
        BAR(); MM(0, 0); BAR();
        // ph6: read B-hi
        RDB(1, 1);
        BAR(); MM(0, 1); BAR();
        // ph7: stage B0(t+3) | read A-hi
        STB(1, 0, s3);
        RDA(1, 1);
        BAR(); MM(1, 0); BAR();
        // ph8: stage A0(t+3) | force tile t+2
        STA(1, 0, s3);
        BAR(); MM(1, 1); VMCNT(4); BAR();
    }

    asm volatile("s_waitcnt vmcnt(0)" ::: "memory");

    // epilogue: row = m0 + wr*128 + mf*16 + l4*4 + r ; col = n0 + wc*64 + nf*16 + l15
    const long long cbase = (long long)z * sC;
#pragma unroll
    for (int mf = 0; mf < 8; ++mf) {
        const int rbase = m0 + wr * 128 + mf * 16 + l4 * 4;
#pragma unroll
        for (int nf = 0; nf < 4; ++nf) {
            const int col = n0 + wc * 64 + nf * 16 + l15;
#pragma unroll
            for (int r = 0; r < 4; ++r) {
                const float v = acc[mf][nf][r];
                const int row = rbase + r;
                if constexpr (EPI == 6) {
                    const int seg = col >> 10, ncol = col & 1023;
                    if (seg == 0) {
                        ((__hip_bfloat16*)Cout)[(long long)row * 1024 + ncol] =
                            __float2bfloat16(v);
                    } else if (seg == 1) {
                        ((__hip_bfloat16*)C2)[(long long)row * 1024 + ncol] =
                            __float2bfloat16(v);
                    } else {
                        const int b = row >> 11, t = row & 2047;
                        ((__hip_bfloat16*)C3)[((long long)b * C_DIM + ncol) * T_DIM + t] =
                            __float2bfloat16(v);
                    }
                } else {
                    const long long idx = cbase + (long long)row * ldc + col;
                    if constexpr (EPI == 0) {
                        ((__hip_bfloat16*)Cout)[idx] = __float2bfloat16(v);
                    } else if constexpr (EPI == 2) {
                        ((float*)Cout)[idx] = v + R[idx];
                    } else if constexpr (EPI == 3) {
                        const float s = v / (1.f + __expf(-v));
                        ((__hip_bfloat16*)Cout)[idx] = __float2bfloat16(s);
                    } else { // EPI == 4
                        ((__hip_bfloat16*)Cout)[idx] = __float2bfloat16(v * scale);
                    }
                }
            }
        }
    }
}

// ---------------------------------------------------------------------------
// RMSNorm: one block per row of C_DIM, fp32 in -> bf16 out
// ---------------------------------------------------------------------------
__global__ __launch_bounds__(256)
void rmsnorm_kernel(const float* __restrict__ x, const float* __restrict__ g,
                    __hip_bfloat16* __restrict__ out)
{
    const long long row = blockIdx.x;
    const int tid = threadIdx.x;
    const float4 v = ((const float4*)(x + row * C_DIM))[tid];
    float ss = v.x * v.x + v.y * v.y + v.z * v.z + v.w * v.w;
#pragma unroll
    for (int off = 32; off; off >>= 1) ss += __shfl_xor(ss, off);
    __shared__ float red[4];
    if ((tid & 63) == 0) red[tid >> 6] = ss;
    __syncthreads();
    ss = red[0] + red[1] + red[2] + red[3];
    const float sc = rsqrtf(ss * (1.0f / C_DIM) + 1e-6f);
    const float4 gv = ((const float4*)g)[tid];
    ushort4 u;
    u.x = f2bf_bits(v.x * sc * gv.x);
    u.y = f2bf_bits(v.y * sc * gv.y);
    u.z = f2bf_bits(v.z * sc * gv.z);
    u.w = f2bf_bits(v.w * sc * gv.w);
    *(ushort4*)(out + row * C_DIM + tid * 4) = u;
}

// ---------------------------------------------------------------------------
// Causal softmax, IN PLACE on bf16 S [B,T,T] -> P bf16 (zeros above diagonal).
// ---------------------------------------------------------------------------
__global__ __launch_bounds__(256)
void softmax_causal(__hip_bfloat16* __restrict__ SP)
{
    const int i = blockIdx.x, b = blockIdx.y;
    __hip_bfloat16* row = SP + ((long long)b * T_DIM + i) * T_DIM;
    const int tid = threadIdx.x;
    const int jbase = tid * 8;

    uint4 raw = ((const uint4*)row)[tid];
    float v[8];
    const unsigned w[4] = {raw.x, raw.y, raw.z, raw.w};
#pragma unroll
    for (int c = 0; c < 4; ++c) {
        unsigned lo = w[c] << 16;
        unsigned hi = w[c] & 0xFFFF0000u;
        v[2 * c]     = __uint_as_float(lo);
        v[2 * c + 1] = __uint_as_float(hi);
    }
#pragma unroll
    for (int e = 0; e < 8; ++e)
        if (jbase + e > i) v[e] = -1e30f;

    float m = v[0];
#pragma unroll
    for (int e = 1; e < 8; ++e) m = fmaxf(m, v[e]);
#pragma unroll
    for (int off = 32; off; off >>= 1) m = fmaxf(m, __shfl_xor(m, off));
    __shared__ float redm[4], reds[4];
    if ((tid & 63) == 0) redm[tid >> 6] = m;
    __syncthreads();
    m = fmaxf(fmaxf(redm[0], redm[1]), fmaxf(redm[2], redm[3]));

    float e8[8];
    float s = 0.f;
#pragma unroll
    for (int e = 0; e < 8; ++e) { e8[e] = __expf(v[e] - m); s += e8[e]; }
#pragma unroll
    for (int off = 32; off; off >>= 1) s += __shfl_xor(s, off);
    if ((tid & 63) == 0) reds[tid >> 6] = s;
    __syncthreads();
    s = reds[0] + reds[1] + reds[2] + reds[3];
    const float inv = 1.f / s;

    uint4 outw;
    unsigned o[4];
#pragma unroll
    for (int c = 0; c < 4; ++c) {
        unsigned lo = f2bf_bits(e8[2 * c] * inv);
        unsigned hi = f2bf_bits(e8[2 * c + 1] * inv);
        o[c] = lo | (hi << 16);
    }
    outw.x = o[0]; outw.y = o[1]; outw.z = o[2]; outw.w = o[3];
    ((uint4*)row)[tid] = outw;
}

// ---------------------------------------------------------------------------
// Weight cast + transpose: in fp32 [K,N] -> out bf16 [N,K]
// ---------------------------------------------------------------------------
__global__ __launch_bounds__(256)
void wcast_t(const float* __restrict__ in, __hip_bfloat16* __restrict__ out,
             int K, int N)
{
    __shared__ float t[32][33];
    const int n0 = blockIdx.x * 32, k0 = blockIdx.y * 32;
    const int tx = threadIdx.x, ty = threadIdx.y;
#pragma unroll
    for (int r = ty; r < 32; r += 8)
        t[r][tx] = in[(long long)(k0 + r) * N + n0 + tx];
    __syncthreads();
#pragma unroll
    for (int r = ty; r < 32; r += 8)
        out[(long long)(n0 + r) * K + k0 + tx] = __float2bfloat16(t[tx][r]);
}

// ---------------------------------------------------------------------------
extern "C" void kernel_launch(void* const* d_in, const int* in_sizes, int n_in,
                              void* d_out, int out_size, void* d_ws, size_t ws_size,
                              hipStream_t stream)
{
    const float* x      = (const float*)d_in[0];
    const float* w_qkv  = (const float*)d_in[1];
    const float* w_proj = (const float*)d_in[2];
    const float* w1     = (const float*)d_in[3];
    const float* w2     = (const float*)d_in[4];
    const float* g1     = (const float*)d_in[5];
    const float* g2     = (const float*)d_in[6];
    float* out = (float*)d_out;
    char* ws = (char*)d_ws;

    const size_t SP_off = 0;                       // S/P bf16 [8,2048,2048] 64MiB
    const size_t h_off  = 0;                       // h bf16 (before S exists)
    const size_t u_off  = 0;                       // u bf16 (after P dead)
    const size_t q_off  = 67108864ull;             // q bf16 -> h2
    const size_t k_off  = 100663296ull;            // k bf16 -> av
    const size_t vT_off = 134217728ull;            // vT bf16 [8,1024,2048]
    const size_t wq_off = 167772160ull;            // 6.29MB
    const size_t wp_off = wq_off + 6291456ull;     // 2.10MB
    const size_t w1_off = wp_off + 2097152ull;     // 4.19MB
    const size_t w2_off = w1_off + 4194304ull;     // 4.19MB
    const size_t NEED   = w2_off + 4194304ull;     // 176 MiB

    if (ws_size < NEED) return;  // guard: fail absmax instead of faulting

    auto bf = [&](size_t off) { return (__hip_bfloat16*)(ws + off); };

    // 1. weights -> bf16 [N,K]
    wcast_t<<<dim3(96, 32), dim3(32, 8), 0, stream>>>(w_qkv,  bf(wq_off), 1024, 3072);
    wcast_t<<<dim3(32, 32), dim3(32, 8), 0, stream>>>(w_proj, bf(wp_off), 1024, 1024);
    wcast_t<<<dim3(64, 32), dim3(32, 8), 0, stream>>>(w1,     bf(w1_off), 1024, 2048);
    wcast_t<<<dim3(32, 64), dim3(32, 8), 0, stream>>>(w2,     bf(w2_off), 2048, 1024);

    // 2. h = rmsnorm(x, g1)
    rmsnorm_kernel<<<16384, 256, 0, stream>>>(x, g1, bf(h_off));

    // 3. fused qkv: q, k, vT = (h @ Wv)^T in one dispatch
    gemm256<6, 0><<<dim3(12, 64, 1), 512, 0, stream>>>(
        bf(h_off), bf(wq_off), bf(q_off), nullptr, bf(k_off), bf(vT_off),
        1024, 1024, 1024, 1024, 0, 0, 0, 1.f);

    // 4. S = q @ k^T * 1/32  (bf16, causal block skip at 256 granularity)
    gemm256<4, 1><<<dim3(8, 8, 8), 512, 0, stream>>>(
        bf(q_off), bf(k_off), bf(SP_off), nullptr, nullptr, nullptr,
        1024, 1024, 1024, 2048,
        (long long)T_DIM * C_DIM, (long long)T_DIM * C_DIM, (long long)T_DIM * T_DIM,
        0.03125f);

    // 5. P = causal softmax(S), in place
    softmax_causal<<<dim3(2048, 8), 256, 0, stream>>>(bf(SP_off));

    // 6. av = P @ V  (vT as Bt, K clipped at diagonal)
    gemm256<0, 2><<<dim3(4, 8, 8), 512, 0, stream>>>(
        bf(SP_off), bf(vT_off), bf(k_off) /*av*/, nullptr, nullptr, nullptr,
        2048, 2048, 2048, 1024,
        (long long)T_DIM * T_DIM, (long long)C_DIM * T_DIM, (long long)T_DIM * C_DIM,
        1.f);

    // 7. x_mid = x + av @ w_proj   (-> d_out)
    gemm256<2, 0><<<dim3(4, 64, 1), 512, 0, stream>>>(
        bf(k_off) /*av*/, bf(wp_off), out, x, nullptr, nullptr,
        1024, 1024, 1024, 1024, 0, 0, 0, 1.f);

    // 8. h2 = rmsnorm(x_mid, g2)   (-> q region)
    rmsnorm_kernel<<<16384, 256, 0, stream>>>(out, g2, bf(q_off));

    // 9. u = silu(h2 @ w1)   (-> SP region, dead)
    gemm256<3, 0><<<dim3(8, 64, 1), 512, 0, stream>>>(
        bf(q_off), bf(w1_off), bf(u_off), nullptr, nullptr, nullptr,
        1024, 1024, 1024, 2048, 0, 0, 0, 1.f);

    // 10. out = x_mid + u @ w2   (in place on d_out)
    gemm256<2, 0><<<dim3(4, 64, 1), 512, 0, stream>>>(
        bf(u_off), bf(w2_off), out, (const float*)out, nullptr, nullptr,
        2048, 2048, 2048, 1024, 0, 0, 0, 1.f);
}

// Round 7
// 569.584 us; speedup vs baseline: 1.0377x; 1.0377x over previous
//
#include <hip/hip_runtime.h>
#include <hip/hip_bf16.h>
#include <stdint.h>

// Transformer block: B=8, T=2048, C=1024, fp32 in/out, bf16 MFMA internally.
// Round 7: pipelined 256x256 GEMM with read-ahead-by-one-phase register flow
// and ONE barrier + ONE vmcnt(0) per K-tile (was 16 barriers / 2-4 vmcnt per
// 2 tiles). Every ds_read completes >=1 phase before its consuming MFMA, so
// LDS service overlaps MFMA instead of serializing with it.
// T1 XCD remap, T2 LDS XOR swizzle, T5 setprio retained.

#define C_DIM 1024
#define T_DIM 2048
#define B_DIM 8

typedef float f32x4 __attribute__((ext_vector_type(4)));
typedef __bf16 bf16x8 __attribute__((ext_vector_type(8)));

typedef const __attribute__((address_space(1))) void gvoid_t;
typedef __attribute__((address_space(3))) void lvoid_t;

__device__ __forceinline__ void gload_lds16(const void* g, void* l) {
    __builtin_amdgcn_global_load_lds((gvoid_t*)g, (lvoid_t*)l, 16, 0, 0);
}

__device__ __forceinline__ unsigned short f2bf_bits(float f) {
    __hip_bfloat16 h = __float2bfloat16(f);
    return *reinterpret_cast<unsigned short*>(&h);
}

// Bijective XCD-chunked remap (m204)
__device__ __forceinline__ void xcd_remap(int& bx, int& by, int& bz) {
    const int gx = gridDim.x, gy = gridDim.y;
    const int nwg = gx * gy * (int)gridDim.z;
    const int orig = bx + gx * (by + gy * bz);
    const int q = nwg >> 3, r = nwg & 7;
    const int xcd = orig & 7, pos = orig >> 3;
    const int neu = (xcd < r ? xcd * (q + 1) : r * (q + 1) + (xcd - r) * q) + pos;
    bx = neu % gx;
    const int t = neu / gx;
    by = t % gy;
    bz = t / gy;
}

#define BAR() do { __builtin_amdgcn_s_barrier(); __builtin_amdgcn_sched_barrier(0); } while(0)
#define VMCNT(n) do { asm volatile("s_waitcnt vmcnt(" #n ")" ::: "memory"); \
                      __builtin_amdgcn_sched_barrier(0); } while(0)

// ds-read A fragments (4 mf x 2 ks) for this wave's rows, 64-row half hq, buf
#define RD_A(dst, buf, hq) do { \
    _Pragma("unroll") \
    for (int mf_ = 0; mf_ < 4; ++mf_) { \
        const char* p_ = lds + (buf)*32768 + wrb + (hq)*8192 + mf_*2048; \
        dst[mf_][0] = *(const bf16x8*)(p_ + offk0); \
        dst[mf_][1] = *(const bf16x8*)(p_ + offk1); \
    } \
} while(0)

// ds-read B fragments (2 n2 x 2 ks) for this wave's cols, N-half nh, buf
#define RD_B(dst, buf, nh) do { \
    _Pragma("unroll") \
    for (int n2_ = 0; n2_ < 2; ++n2_) { \
        const char* p_ = lds + 65536 + (buf)*32768 + wcb + ((nh)*2 + n2_)*2048; \
        dst[n2_][0] = *(const bf16x8*)(p_ + offk0); \
        dst[n2_][1] = *(const bf16x8*)(p_ + offk1); \
    } \
} while(0)

// 16 MFMA for quadrant (Mh,Nh) using reg sets aS/bS
#define MMQ(aS, bS, Mh, Nh) do { \
    __builtin_amdgcn_s_setprio(1); \
    _Pragma("unroll") \
    for (int m4_ = 0; m4_ < 4; ++m4_) \
    _Pragma("unroll") \
    for (int n2_ = 0; n2_ < 2; ++n2_) \
    _Pragma("unroll") \
    for (int ks_ = 0; ks_ < 2; ++ks_) \
        acc[(Mh)*4 + m4_][(Nh)*2 + n2_] = __builtin_amdgcn_mfma_f32_16x16x32_bf16( \
            aS[m4_][ks_], bS[n2_][ks_], acc[(Mh)*4 + m4_][(Nh)*2 + n2_], 0, 0, 0); \
    __builtin_amdgcn_s_setprio(0); \
} while(0)

// stage one 16KB half-tile (2 x gload_lds16 per thread)
#define STA(buf, half, kt) do { \
    const int go_ = aoff + (half)*128*lda + (kt)*64; \
    char* lp_ = ldsw + (buf)*32768 + (half)*16384; \
    gload_lds16(A + go_,            lp_); \
    gload_lds16(A + go_ + 64*lda,   lp_ + 8192); \
} while(0)
#define STB(buf, half, kt) do { \
    const int go_ = boff + (half)*128*ldb + (kt)*64; \
    char* lp_ = ldsw + 65536 + (buf)*32768 + (half)*16384; \
    gload_lds16(Bt + go_,           lp_); \
    gload_lds16(Bt + go_ + 64*ldb,  lp_ + 8192); \
} while(0)
// full K-tile stage: A both halves + B both halves (8 gload_lds / thread)
#define STAGE4(buf, kt) do { STA(buf,0,kt); STA(buf,1,kt); STB(buf,0,kt); STB(buf,1,kt); } while(0)

// ---------------------------------------------------------------------------
// 256x256 GEMM: C[M,N] = A[M,K] x Bt[N,K], bf16 in. BK=64, 8 waves (2Mx4N).
// Per K-tile t (buf = t&1), 4 quadrant phases; reads run one phase ahead:
//   Q0: rd bH(t)      | MFMA(aP,bL)   (aP=aLo(t), bL=bLo(t) read at Q3(t-1))
//   Q1: rd aQ=aHi(t)  | MFMA(aP,bH)
//   Q2:               | MFMA(aQ,bL)
//   Q3: VMCNT(0)+BAR  -> stage tile t+2 into buf | rd aP=aLo(t+1), bL=bLo(t+1)
//       | MFMA(aQ,bH)
// Hazards at the single Q3 sync point: vmcnt(0) before barrier => when all
// waves pass, ALL staging landed (RAW for buf(t+1) reads); each wave's
// buf(t)-reads completed before its barrier arrival (lgkm waits precede it),
// so restaging buf(t) after the barrier is WAR-safe.
// EPI: 0 bf16; 2 fp32 + residual R (Cout may alias R); 3 bf16 silu;
//      4 bf16*scale; 6 fused qkv route (Cout=q, C2=k, C3=vT[B][C][T]).
// CMODE: 0 none; 1 causal block skip; 2 causal K clip (kmax = m0+256).
// ---------------------------------------------------------------------------
template<int EPI, int CMODE>
__global__ __launch_bounds__(512, 2)
void gemm256(const __hip_bfloat16* A, const __hip_bfloat16* Bt,
             void* Cout, const float* R, void* C2, void* C3,
             int K, int lda, int ldb, int ldc,
             long long sA, long long sB, long long sC, float scale)
{
    int bx = blockIdx.x, by = blockIdx.y, bz = blockIdx.z;
    xcd_remap(bx, by, bz);
    if constexpr (CMODE == 1) { if (bx > by) return; }

    const int tid  = threadIdx.x;
    const int lane = tid & 63, wave = tid >> 6;
    const int l15  = lane & 15, l4 = lane >> 4;
    const int wr   = wave >> 2, wc = wave & 3;      // 2 x 4 wave grid
    const int m0   = by * 256, n0 = bx * 256;
    const int z    = bz;

    A  += (long long)z * sA;
    Bt += (long long)z * sB;

    __shared__ __align__(16) char lds_[131072];     // A [0,64K), B [64K,128K)
    char* lds  = lds_;
    char* ldsw = lds_ + wave * 1024;

    int kmax = K;
    if constexpr (CMODE == 2) { int km = m0 + 256; kmax = km < K ? km : K; }
    const int NT = kmax >> 6, niter = NT >> 1;      // NT even for all our shapes

    // read-side lane offsets: row-local byte = l15*128 + ((ks*4+l4)^(l15&7))*16
    const int offk0 = l15 * 128 + (((l4)     ^ (l15 & 7)) << 4);
    const int offk1 = l15 * 128 + (((4 + l4) ^ (l15 & 7)) << 4);
    const int wrb = wr * 16384, wcb = wc * 8192;

    // staging: thread -> (row = tid>>3, slot = (tid&7)^(row&7)); inverse swizzle on src
    const int rowq  = tid >> 3;
    const int sslot = (tid & 7) ^ (rowq & 7);
    const int aoff  = (m0 + rowq) * lda + sslot * 8;
    const int boff  = (n0 + rowq) * ldb + sslot * 8;

    f32x4 acc[8][4];
#pragma unroll
    for (int i = 0; i < 8; ++i)
#pragma unroll
        for (int j = 0; j < 4; ++j) acc[i][j] = (f32x4){0.f, 0.f, 0.f, 0.f};
    bf16x8 aP[4][2], aQ[4][2], bL[2][2], bH[2][2];

    // prologue: stage tiles 0,1; wait tile0 only; preload Q0(t=0) operands
    STAGE4(0, 0);
    STAGE4(1, 1);
    VMCNT(8);
    BAR();
    RD_A(aP, 0, 0);
    RD_B(bL, 0, 0);

    for (int it = 0; it < niter; ++it) {
        const int t0 = 2 * it, t1 = 2 * it + 1;
        // ---- tile t0 (buf0) ----
        RD_B(bH, 0, 1);            MMQ(aP, bL, 0, 0);      // Q0
        RD_A(aQ, 0, 1);            MMQ(aP, bH, 0, 1);      // Q1
                                   MMQ(aQ, bL, 1, 0);      // Q2
        VMCNT(0); BAR();                                    // Q3 sync
        if (t0 + 2 < NT) STAGE4(0, t0 + 2);
        RD_A(aP, 1, 0);            // aLo(t1)
        RD_B(bL, 1, 0);            // bLo(t1)
                                   MMQ(aQ, bH, 1, 1);      // Q3
        // ---- tile t1 (buf1) ----
        RD_B(bH, 1, 1);            MMQ(aP, bL, 0, 0);
        RD_A(aQ, 1, 1);            MMQ(aP, bH, 0, 1);
                                   MMQ(aQ, bL, 1, 0);
        VMCNT(0); BAR();
        if (t1 + 2 < NT) STAGE4(1, t1 + 2);
        if (it + 1 < niter) {
            RD_A(aP, 0, 0);
            RD_B(bL, 0, 0);
        }
                                   MMQ(aQ, bH, 1, 1);
    }

    asm volatile("s_waitcnt vmcnt(0)" ::: "memory");

    // epilogue: row = m0 + wr*128 + mf*16 + l4*4 + r ; col = n0 + wc*64 + nf*16 + l15
    const long long cbase = (long long)z * sC;
#pragma unroll
    for (int mf = 0; mf < 8; ++mf) {
        const int rbase = m0 + wr * 128 + mf * 16 + l4 * 4;
#pragma unroll
        for (int nf = 0; nf < 4; ++nf) {
            const int col = n0 + wc * 64 + nf * 16 + l15;
#pragma unroll
            for (int r = 0; r < 4; ++r) {
                const float v = acc[mf][nf][r];
                const int row = rbase + r;
                if constexpr (EPI == 6) {
                    const int seg = col >> 10, ncol = col & 1023;
                    if (seg == 0) {
                        ((__hip_bfloat16*)Cout)[(long long)row * 1024 + ncol] =
                            __float2bfloat16(v);
                    } else if (seg == 1) {
                        ((__hip_bfloat16*)C2)[(long long)row * 1024 + ncol] =
                            __float2bfloat16(v);
                    } else {
                        const int b = row >> 11, t = row & 2047;
                        ((__hip_bfloat16*)C3)[((long long)b * C_DIM + ncol) * T_DIM + t] =
                            __float2bfloat16(v);
                    }
                } else {
                    const long long idx = cbase + (long long)row * ldc + col;
                    if constexpr (EPI == 0) {
                        ((__hip_bfloat16*)Cout)[idx] = __float2bfloat16(v);
                    } else if constexpr (EPI == 2) {
                        ((float*)Cout)[idx] = v + R[idx];
                    } else if constexpr (EPI == 3) {
                        const float s = v / (1.f + __expf(-v));
                        ((__hip_bfloat16*)Cout)[idx] = __float2bfloat16(s);
                    } else { // EPI == 4
                        ((__hip_bfloat16*)Cout)[idx] = __float2bfloat16(v * scale);
                    }
                }
            }
        }
    }
}

// ---------------------------------------------------------------------------
// RMSNorm: one block per row of C_DIM, fp32 in -> bf16 out
// ---------------------------------------------------------------------------
__global__ __launch_bounds__(256)
void rmsnorm_kernel(const float* __restrict__ x, const float* __restrict__ g,
                    __hip_bfloat16* __restrict__ out)
{
    const long long row = blockIdx.x;
    const int tid = threadIdx.x;
    const float4 v = ((const float4*)(x + row * C_DIM))[tid];
    float ss = v.x * v.x + v.y * v.y + v.z * v.z + v.w * v.w;
#pragma unroll
    for (int off = 32; off; off >>= 1) ss += __shfl_xor(ss, off);
    __shared__ float red[4];
    if ((tid & 63) == 0) red[tid >> 6] = ss;
    __syncthreads();
    ss = red[0] + red[1] + red[2] + red[3];
    const float sc = rsqrtf(ss * (1.0f / C_DIM) + 1e-6f);
    const float4 gv = ((const float4*)g)[tid];
    ushort4 u;
    u.x = f2bf_bits(v.x * sc * gv.x);
    u.y = f2bf_bits(v.y * sc * gv.y);
    u.z = f2bf_bits(v.z * sc * gv.z);
    u.w = f2bf_bits(v.w * sc * gv.w);
    *(ushort4*)(out + row * C_DIM + tid * 4) = u;
}

// ---------------------------------------------------------------------------
// Causal softmax, IN PLACE on bf16 S [B,T,T] -> P bf16 (zeros above diagonal).
// ---------------------------------------------------------------------------
__global__ __launch_bounds__(256)
void softmax_causal(__hip_bfloat16* __restrict__ SP)
{
    const int i = blockIdx.x, b = blockIdx.y;
    __hip_bfloat16* row = SP + ((long long)b * T_DIM + i) * T_DIM;
    const int tid = threadIdx.x;
    const int jbase = tid * 8;

    uint4 raw = ((const uint4*)row)[tid];
    float v[8];
    const unsigned w[4] = {raw.x, raw.y, raw.z, raw.w};
#pragma unroll
    for (int c = 0; c < 4; ++c) {
        unsigned lo = w[c] << 16;
        unsigned hi = w[c] & 0xFFFF0000u;
        v[2 * c]     = __uint_as_float(lo);
        v[2 * c + 1] = __uint_as_float(hi);
    }
#pragma unroll
    for (int e = 0; e < 8; ++e)
        if (jbase + e > i) v[e] = -1e30f;

    float m = v[0];
#pragma unroll
    for (int e = 1; e < 8; ++e) m = fmaxf(m, v[e]);
#pragma unroll
    for (int off = 32; off; off >>= 1) m = fmaxf(m, __shfl_xor(m, off));
    __shared__ float redm[4], reds[4];
    if ((tid & 63) == 0) redm[tid >> 6] = m;
    __syncthreads();
    m = fmaxf(fmaxf(redm[0], redm[1]), fmaxf(redm[2], redm[3]));

    float e8[8];
    float s = 0.f;
#pragma unroll
    for (int e = 0; e < 8; ++e) { e8[e] = __expf(v[e] - m); s += e8[e]; }
#pragma unroll
    for (int off = 32; off; off >>= 1) s += __shfl_xor(s, off);
    if ((tid & 63) == 0) reds[tid >> 6] = s;
    __syncthreads();
    s = reds[0] + reds[1] + reds[2] + reds[3];
    const float inv = 1.f / s;

    uint4 outw;
    unsigned o[4];
#pragma unroll
    for (int c = 0; c < 4; ++c) {
        unsigned lo = f2bf_bits(e8[2 * c] * inv);
        unsigned hi = f2bf_bits(e8[2 * c + 1] * inv);
        o[c] = lo | (hi << 16);
    }
    outw.x = o[0]; outw.y = o[1]; outw.z = o[2]; outw.w = o[3];
    ((uint4*)row)[tid] = outw;
}

// ---------------------------------------------------------------------------
// Weight cast + transpose: in fp32 [K,N] -> out bf16 [N,K]
// ---------------------------------------------------------------------------
__global__ __launch_bounds__(256)
void wcast_t(const float* __restrict__ in, __hip_bfloat16* __restrict__ out,
             int K, int N)
{
    __shared__ float t[32][33];
    const int n0 = blockIdx.x * 32, k0 = blockIdx.y * 32;
    const int tx = threadIdx.x, ty = threadIdx.y;
#pragma unroll
    for (int r = ty; r < 32; r += 8)
        t[r][tx] = in[(long long)(k0 + r) * N + n0 + tx];
    __syncthreads();
#pragma unroll
    for (int r = ty; r < 32; r += 8)
        out[(long long)(n0 + r) * K + k0 + tx] = __float2bfloat16(t[tx][r]);
}

// ---------------------------------------------------------------------------
extern "C" void kernel_launch(void* const* d_in, const int* in_sizes, int n_in,
                              void* d_out, int out_size, void* d_ws, size_t ws_size,
                              hipStream_t stream)
{
    const float* x      = (const float*)d_in[0];
    const float* w_qkv  = (const float*)d_in[1];
    const float* w_proj = (const float*)d_in[2];
    const float* w1     = (const float*)d_in[3];
    const float* w2     = (const float*)d_in[4];
    const float* g1     = (const float*)d_in[5];
    const float* g2     = (const float*)d_in[6];
    float* out = (float*)d_out;
    char* ws = (char*)d_ws;

    const size_t SP_off = 0;                       // S/P bf16 [8,2048,2048] 64MiB
    const size_t h_off  = 0;                       // h bf16 (before S exists)
    const size_t u_off  = 0;                       // u bf16 (after P dead)
    const size_t q_off  = 67108864ull;             // q bf16 -> h2
    const size_t k_off  = 100663296ull;            // k bf16 -> av
    const size_t vT_off = 134217728ull;            // vT bf16 [8,1024,2048]
    const size_t wq_off = 167772160ull;            // 6.29MB
    const size_t wp_off = wq_off + 6291456ull;     // 2.10MB
    const size_t w1_off = wp_off + 2097152ull;     // 4.19MB
    const size_t w2_off = w1_off + 4194304ull;     // 4.19MB
    const size_t NEED   = w2_off + 4194304ull;     // 176 MiB

    if (ws_size < NEED) return;  // guard: fail absmax instead of faulting

    auto bf = [&](size_t off) { return (__hip_bfloat16*)(ws + off); };

    // 1. weights -> bf16 [N,K]
    wcast_t<<<dim3(96, 32), dim3(32, 8), 0, stream>>>(w_qkv,  bf(wq_off), 1024, 3072);
    wcast_t<<<dim3(32, 32), dim3(32, 8), 0, stream>>>(w_proj, bf(wp_off), 1024, 1024);
    wcast_t<<<dim3(64, 32), dim3(32, 8), 0, stream>>>(w1,     bf(w1_off), 1024, 2048);
    wcast_t<<<dim3(32, 64), dim3(32, 8), 0, stream>>>(w2,     bf(w2_off), 2048, 1024);

    // 2. h = rmsnorm(x, g1)
    rmsnorm_kernel<<<16384, 256, 0, stream>>>(x, g1, bf(h_off));

    // 3. fused qkv: q, k, vT = (h @ Wv)^T in one dispatch
    gemm256<6, 0><<<dim3(12, 64, 1), 512, 0, stream>>>(
        bf(h_off), bf(wq_off), bf(q_off), nullptr, bf(k_off), bf(vT_off),
        1024, 1024, 1024, 1024, 0, 0, 0, 1.f);

    // 4. S = q @ k^T * 1/32  (bf16, causal block skip at 256 granularity)
    gemm256<4, 1><<<dim3(8, 8, 8), 512, 0, stream>>>(
        bf(q_off), bf(k_off), bf(SP_off), nullptr, nullptr, nullptr,
        1024, 1024, 1024, 2048,
        (long long)T_DIM * C_DIM, (long long)T_DIM * C_DIM, (long long)T_DIM * T_DIM,
        0.03125f);

    // 5. P = causal softmax(S), in place
    softmax_causal<<<dim3(2048, 8), 256, 0, stream>>>(bf(SP_off));

    // 6. av = P @ V  (vT as Bt, K clipped at diagonal)
    gemm256<0, 2><<<dim3(4, 8, 8), 512, 0, stream>>>(
        bf(SP_off), bf(vT_off), bf(k_off) /*av*/, nullptr, nullptr, nullptr,
        2048, 2048, 2048, 1024,
        (long long)T_DIM * T_DIM, (long long)C_DIM * T_DIM, (long long)T_DIM * C_DIM,
        1.f);

    // 7. x_mid = x + av @ w_proj   (-> d_out)
    gemm256<2, 0><<<dim3(4, 64, 1), 512, 0, stream>>>(
        bf(k_off) /*av*/, bf(wp_off), out, x, nullptr, nullptr,
        1024, 1024, 1024, 1024, 0, 0, 0, 1.f);

    // 8. h2 = rmsnorm(x_mid, g2)   (-> q region)
    rmsnorm_kernel<<<16384, 256, 0, stream>>>(out, g2, bf(q_off));

    // 9. u = silu(h2 @ w1)   (-> SP region, dead)
    gemm256<3, 0><<<dim3(8, 64, 1), 512, 0, stream>>>(
        bf(q_off), bf(w1_off), bf(u_off), nullptr, nullptr, nullptr,
        1024, 1024, 1024, 2048, 0, 0, 0, 1.f);

    // 10. out = x_mid + u @ w2   (in place on d_out)
    gemm256<2, 0><<<dim3(4, 64, 1), 512, 0, stream>>>(
        bf(u_off), bf(w2_off), out, (const float*)out, nullptr, nullptr,
        2048, 2048, 2048, 1024, 0, 0, 0, 1.f);
}